// Round 5
// baseline (356.480 us; speedup 1.0000x reference)
//
#include <hip/hip_runtime.h>
#include <hip/hip_bf16.h>

// Problem constants
#define BB 8
#define NN 8192
#define CC 64
#define PP 2048
#define KK 16
#define H1 64
#define H2 128
#define H1STR 76                        // h1 row stride (shorts): 32-bank-spread writes

typedef float  f32x4 __attribute__((ext_vector_type(4)));
typedef short  s16x8 __attribute__((ext_vector_type(8)));

// ---- workspace layout (bytes) ----
#define OFF_FXT   0u                    // B*N rows of 72 bf16 = 9,437,184
#define OFF_PTS4  17825792u             // B*N float4 = 2,097,152
#define OFF_W1P   20971520u             // 64*192 bf16 ([n][0:96)=W1a*s, [n][96:192)=(W1b-W1a)*s)
#define OFF_W2P   20996096u             // 128*72 bf16
#define OFF_C1    21014528u             // 64 f32
#define OFF_C2    21014784u             // 128 f32
#define OFF_FLG   21016576u             // 256 dwords: per-block done flags

#define FLTMAX 3.402823466e+38f
#define MAGIC 0x9E3779B1u

static __device__ __forceinline__ unsigned short bf16b(float v) {
    __hip_bfloat16 h = __float2bfloat16(v);
    return *reinterpret_cast<unsigned short*>(&h);
}
static __device__ __forceinline__ unsigned pk2(float a, float b) {
    return ((unsigned)bf16b(b) << 16) | (unsigned)bf16b(a);
}
static __device__ __forceinline__ s16x8 as8(uint4 v) {
    union { uint4 u; s16x8 s; } x; x.u = v; return x.s;
}
// wave-local LDS fence: compiler barrier + LDS drain, NO vmcnt drain
#define LDS_FENCE() asm volatile("s_waitcnt lgkmcnt(0)" ::: "memory")

// ---------------- single kernel, flag-synced (no cooperative launch) ----
// 256 blocks x 1024 thr = 1 block/CU -> all blocks co-resident by capacity
// (LDS 151.5KB, VGPR<=128), so device-scope flag handshakes are deadlock-free
// (Phase T never waits). Phase T: transpose 256 rows -> fxtb + pts4 + fold
// slice, then release-store flag[blk]. Phase A waits only its batch's 32
// pts4 flags (skew ~0), stages from pts4 (coalesced b128), runs KNN; knn
// indices stay in LDS. Phase B waits all 256 flags (fxtb + fold complete).
// b = blockIdx&7 pins batch -> XCD: fxtb/pts4 written and read on same XCD.
__global__ __launch_bounds__(1024, 1) void kfused(
    const float* __restrict__ xyz,  const float* __restrict__ feat,
    const float* __restrict__ W1,   const float* __restrict__ b1,
    const float* __restrict__ g1,   const float* __restrict__ be1,
    const float* __restrict__ m1,   const float* __restrict__ v1,
    const float* __restrict__ W2,   const float* __restrict__ b2,
    const float* __restrict__ g2,   const float* __restrict__ be2,
    const float* __restrict__ m2,   const float* __restrict__ v2,
    unsigned* __restrict__ fxtb,    float4* __restrict__ pts4,
    unsigned short* __restrict__ w1p, unsigned short* __restrict__ w2p,
    float* __restrict__ c1,         float* __restrict__ c2,
    unsigned* __restrict__ flags,
    float* __restrict__ out0, float* __restrict__ out1, float* __restrict__ out2) {

    __shared__ __align__(16) char smem[131072];
    __shared__ float2 scratch[16][2][64];    // 16 KB dual per-wave buffers
    __shared__ int knnl[16][64];             // 4 KB: per-wave [4 queries][16 ranks]
    int lane = threadIdx.x & 63;
    int wv   = threadIdx.x >> 6;
    int b    = blockIdx.x & 7;               // XCD-aware batch assignment
    int g    = blockIdx.x >> 3;              // query-group 0..31
    int q0base = g * 64;
    size_t pb = (size_t)b * NN;

    // ================= Phase T: transpose 4 tiles -> fxtb/pts4, fold =======
    {
        float (*tile)[72][65] = (float (*)[72][65])smem;   // 74,880 B
        int grp = threadIdx.x >> 8;          // 0..3 (one 64-pt tile each)
        int t256 = threadIdx.x & 255;
        int tx = t256 & 63, ty = t256 >> 6;  // ty 0..3
        int n0 = (g * 4 + grp) * 64;
        for (int c = ty; c < 72; c += 4) {
            float v;
            if (c < 64)       v = feat[((size_t)b * 64 + c) * NN + n0 + tx];
            else if (c < 67)  v = xyz[((size_t)b * NN + n0 + tx) * 3 + (c - 64)];
            else              v = 0.f;                 // pad cols 67..71
            tile[grp][c][tx] = v;
        }
        // weight fold slice (21,696 elems over 256 blocks), hidden in T latency
        if (threadIdx.x < 85) {
            int i = blockIdx.x * 85 + threadIdx.x;
            if (i < 6144) {                      // W1a folded: [64][96]
                int n = i / 96, c = i - n * 96;
                float s = g1[n] * rsqrtf(v1[n] + 1e-5f);
                w1p[n * 192 + c] = bf16b((c < 67) ? W1[n * 134 + c] * s : 0.f);
            } else if (i < 12288) {              // W1d = (W1b-W1a)*s at +96
                int j = i - 6144;
                int n = j / 96, c = j - n * 96;
                float s = g1[n] * rsqrtf(v1[n] + 1e-5f);
                w1p[n * 192 + 96 + c] =
                    bf16b((c < 67) ? (W1[n * 134 + 67 + c] - W1[n * 134 + c]) * s : 0.f);
            } else if (i < 21504) {              // W2 folded: [128][72]
                int j = i - 12288;
                int o = j / 72, k = j - o * 72;
                float s = g2[o] * rsqrtf(v2[o] + 1e-5f);
                w2p[j] = bf16b((k < 64) ? W2[o * 64 + k] * s : 0.f);
            } else if (i < 21568) {
                int l = i - 21504;
                float s = g1[l] * rsqrtf(v1[l] + 1e-5f);
                c1[l] = s * (b1[l] - m1[l]) + be1[l];
            } else if (i < 21696) {
                int p = i - 21568;
                float s = g2[p] * rsqrtf(v2[p] + 1e-5f);
                c2[p] = s * (b2[p] - m2[p]) + be2[p];
            }
        }
        __syncthreads();
        size_t base = ((size_t)b * NN + n0) * 36;   // 36 dwords (72 bf16) per row
        for (int e = t256; e < 64 * 36; e += 256) {
            int nl = e / 36, c = e - nl * 36;
            fxtb[base + e] = pk2(tile[grp][2 * c][nl], tile[grp][2 * c + 1][nl]);
        }
        if (t256 < 64) {                 // pts4 from already-staged xyz cols
            float x = tile[grp][64][t256], y = tile[grp][65][t256], z = tile[grp][66][t256];
            pts4[pb + n0 + t256] = make_float4(x, y, z, x * x + y * y + z * z);
        }
        if (n0 < PP) {
            if (t256 < 64)
                out2[b * PP + n0 + t256] = (float)(n0 + t256);
            for (int e = t256; e < 64 * 3; e += 256) {
                int nl = e / 3, d = e - nl * 3;
                out0[((size_t)b * PP + n0 + nl) * 3 + d] = tile[grp][64 + d][nl];
            }
        }
        __syncthreads();   // tile dead (stage overlay safe) + all stores issued
        if (threadIdx.x == 0) {
            __threadfence();             // device-scope release of fxtb/pts4/fold
            __hip_atomic_store(flags + blockIdx.x, MAGIC,
                               __ATOMIC_RELEASE, __HIP_MEMORY_SCOPE_AGENT);
        }
    }

    // wait for this batch's 32 pts4 producers (all blocks run T concurrently)
    {
        bool ok;
        do {
            unsigned v = MAGIC;
            if (lane < 32)
                v = __hip_atomic_load(flags + (lane * 8 + b),
                                      __ATOMIC_ACQUIRE, __HIP_MEMORY_SCOPE_AGENT);
            ok = __all(v == MAGIC);
        } while (!ok);
    }

    // ================= Phase A: KNN =================
    {
        float4* stage = (float4*)smem;       // swizzled slot(r,c)=r*64+((c+(r>>1))&63)
        int q0 = q0base + wv * 4;

        float4 qc = make_float4(0.f, 0.f, 0.f, 0.f);
        if (lane < 4) qc = pts4[pb + q0 + lane];
        float qx2 = -2.f * qc.x, qy2 = -2.f * qc.y, qz2 = -2.f * qc.z;
        float bx[4], by[4], bz[4];
#pragma unroll
        for (int q = 0; q < 4; ++q) {
            bx[q] = __shfl(qx2, q); by[q] = __shfl(qy2, q); bz[q] = __shfl(qz2, q);
        }

        // stage all 8192 points (coalesced b128 from pts4)
#pragma unroll
        for (int i = 0; i < 8; ++i) {
            int p = i * 1024 + threadIdx.x;
            float4 v = pts4[pb + p];
            int r = p >> 6, c = p & 63;
            stage[(r << 6) | ((c + (r >> 1)) & 63)] = v;
        }
        __syncthreads();

        // Phase 1: per-lane min over its 128 candidates (rows 2L, 2L+1)
        float m[4];
#pragma unroll
        for (int q = 0; q < 4; ++q) m[q] = FLTMAX;
#pragma unroll
        for (int rr = 0; rr < 2; ++rr) {
            int rowbase = (2 * lane + rr) << 6;
#pragma unroll
            for (int j8 = 0; j8 < 8; ++j8) {
                float4 cc[8];
#pragma unroll
                for (int i = 0; i < 8; ++i)
                    cc[i] = stage[rowbase | ((j8 * 8 + i + lane) & 63)];
#pragma unroll
                for (int q = 0; q < 4; ++q) {
                    float x = bx[q], y = by[q], z = bz[q];
#pragma unroll
                    for (int i = 0; i < 8; i += 2) {
                        float e0 = fmaf(z, cc[i].z, fmaf(y, cc[i].y, fmaf(x, cc[i].x, cc[i].w)));
                        float e1 = fmaf(z, cc[i+1].z, fmaf(y, cc[i+1].y, fmaf(x, cc[i+1].x, cc[i+1].w)));
                        m[q] = fminf(fminf(m[q], e0), e1);
                    }
                }
            }
        }

        // Interleaved threshold sorts: T[q] = 16th smallest of 64 lane-mins
        float sv0 = m[0], sv1 = m[1], sv2 = m[2], sv3 = m[3];
#pragma unroll
        for (int k = 2; k <= 64; k <<= 1) {
#pragma unroll
            for (int j = k >> 1; j > 0; j >>= 1) {
                bool keepMin = (((lane & k) == 0) == ((lane & j) == 0));
                float p0 = __shfl_xor(sv0, j, 64);
                float p1 = __shfl_xor(sv1, j, 64);
                float p2 = __shfl_xor(sv2, j, 64);
                float p3 = __shfl_xor(sv3, j, 64);
                sv0 = keepMin ? fminf(sv0, p0) : fmaxf(sv0, p0);
                sv1 = keepMin ? fminf(sv1, p1) : fmaxf(sv1, p1);
                sv2 = keepMin ? fminf(sv2, p2) : fmaxf(sv2, p2);
                sv3 = keepMin ? fminf(sv3, p3) : fmaxf(sv3, p3);
            }
        }
        float T[4];
        T[0] = __shfl(sv0, 15, 64); T[1] = __shfl(sv1, 15, 64);
        T[2] = __shfl(sv2, 15, 64); T[3] = __shfl(sv3, 15, 64);

        unsigned long long below = (lane == 63) ? 0x7FFFFFFFFFFFFFFFull
                                                : ((1ull << lane) - 1ull);
#pragma unroll
        for (int pr = 0; pr < 4; pr += 2) {
            int Ms[2];
#pragma unroll
            for (int u = 0; u < 2; ++u) {
                int q = pr + u;
                float x = bx[q], y = by[q], z = bz[q], tq = T[q];
                unsigned long long rm = __ballot(m[q] <= tq);
                int cnt = 0;
                while (rm) {
                    int sl = __ffsll((long long)rm) - 1; rm &= rm - 1;
                    int phys = (lane + sl) & 63;
                    float4 c0 = stage[((2 * sl) << 6) | phys];
                    float4 c1v_ = stage[((2 * sl + 1) << 6) | phys];
                    float e0 = fmaf(z, c0.z, fmaf(y, c0.y, fmaf(x, c0.x, c0.w)));
                    float e1 = fmaf(z, c1v_.z, fmaf(y, c1v_.y, fmaf(x, c1v_.x, c1v_.w)));
                    unsigned long long b0 = __ballot(e0 <= tq);
                    if (e0 <= tq) {
                        int pos = cnt + __popcll(b0 & below);
                        if (pos < 64)
                            scratch[wv][u][pos] = make_float2(e0, __int_as_float(sl * 128 + lane));
                    }
                    cnt += __popcll(b0);
                    unsigned long long b1 = __ballot(e1 <= tq);
                    if (e1 <= tq) {
                        int pos = cnt + __popcll(b1 & below);
                        if (pos < 64)
                            scratch[wv][u][pos] = make_float2(e1, __int_as_float(sl * 128 + 64 + lane));
                    }
                    cnt += __popcll(b1);
                }
                Ms[u] = min(cnt, 64);
            }
            LDS_FENCE();   // drain compaction writes before readback
#pragma unroll
            for (int u = 0; u < 2; ++u) {
                int M = Ms[u];
                float2 own = scratch[wv][u][lane];
                float di = own.x; int ni = __float_as_int(own.y);
                int rank = 0;
                const float2* buf = &scratch[wv][u][0];
#pragma unroll 4
                for (int j = 0; j < M; ++j) {
                    float2 e = buf[j];
                    int nj = __float_as_int(e.y);
                    rank += (e.x < di || (e.x == di && nj < ni)) ? 1 : 0;
                }
                if (lane < M && rank < 16)
                    knnl[wv][(pr + u) * 16 + rank] = ni;   // LDS, not global
            }
            LDS_FENCE();   // order scratch reuse across pairs
        }
    }

    // all 64 knn indices for this wave's 4 queries (wave-local LDS)
    int idxAll = knnl[wv][lane];

    __syncthreads();   // stage buffer dead -> safe to overlay

    // wait for ALL 256 blocks (fxtb rows of every batch + full weight fold)
    {
        bool ok;
        do {
            unsigned v0 = __hip_atomic_load(flags + lane,       __ATOMIC_ACQUIRE, __HIP_MEMORY_SCOPE_AGENT);
            unsigned v1 = __hip_atomic_load(flags + 64 + lane,  __ATOMIC_ACQUIRE, __HIP_MEMORY_SCOPE_AGENT);
            unsigned v2_ = __hip_atomic_load(flags + 128 + lane, __ATOMIC_ACQUIRE, __HIP_MEMORY_SCOPE_AGENT);
            unsigned v3 = __hip_atomic_load(flags + 192 + lane, __ATOMIC_ACQUIRE, __HIP_MEMORY_SCOPE_AGENT);
            ok = __all(v0 == MAGIC && v1 == MAGIC && v2_ == MAGIC && v3 == MAGIC);
        } while (!ok);
    }

    // ================= Phase B: MLP =================
    unsigned short* w1a   = (unsigned short*)smem;             // [64][104]
    unsigned short* h1all = (unsigned short*)(smem + 13312);   // 16 x [16][H1STR]
    unsigned short* w2l   = (unsigned short*)(smem + 52224);   // [128][88]
    float*          otile = (float*)(smem + 74752);            // [64][130]
    int col = lane & 15, quad = lane >> 4;
    const uint4* fx4 = (const uint4*)fxtb;
    size_t rowb = (size_t)b * NN;

    // stage weights into LDS (all 1024 threads)
    {
        const unsigned* src1 = (const unsigned*)w1p;   // rows: 96 dw stride
        unsigned* d1 = (unsigned*)w1a;
        for (int t = threadIdx.x; t < 64 * 48; t += 1024) {
            int r = t / 48, c = t - r * 48;
            d1[r * 52 + c] = src1[r * 96 + c];
        }
        const unsigned* src2 = (const unsigned*)w2p;   // rows: 36 dw
        unsigned* d2 = (unsigned*)w2l;
        for (int t = threadIdx.x; t < 128 * 36; t += 1024) {
            int r = t / 36, c = t - r * 36;
            d2[r * 44 + c] = src2[r * 36 + c];
        }
    }

    // qterm: f_q . W1d for this wave's 4 queries (W1d fragments from global)
    f32x4 accq[4];
#pragma unroll
    for (int nt = 0; nt < 4; ++nt) accq[nt] = (f32x4){0.f, 0.f, 0.f, 0.f};
    {
        const uint4* rp = fx4 + (rowb + q0base + wv * 4 + col) * 9;
        uint4 qf0 = rp[quad];
        uint4 qf1 = rp[4 + quad];
        uint4 qf2 = rp[8];
        if (quad != 0) qf2 = make_uint4(0u, 0u, 0u, 0u);
        uint4 qf[3] = {qf0, qf1, qf2};
#pragma unroll
        for (int ks = 0; ks < 3; ++ks) {
            s16x8 a = as8(qf[ks]);
#pragma unroll
            for (int nt = 0; nt < 4; ++nt) {
                s16x8 bfr = *(const s16x8*)(w1p + (nt * 16 + col) * 192 + 96 + ks * 32 + quad * 8);
                accq[nt] = __builtin_amdgcn_mfma_f32_16x16x32_bf16(a, bfr, accq[nt], 0, 0, 0);
            }
        }
    }
    float qcc[4][4];   // qterm + c1, per (query, nt)
    {
        float c1v[4];
#pragma unroll
        for (int nt = 0; nt < 4; ++nt) c1v[nt] = c1[nt * 16 + col];
#pragma unroll
        for (int qi = 0; qi < 4; ++qi)
#pragma unroll
            for (int nt = 0; nt < 4; ++nt)
                qcc[qi][nt] = __shfl(accq[nt][qi], col, 64) + c1v[nt];
    }
    float c2v[8];
#pragma unroll
    for (int nt = 0; nt < 8; ++nt) c2v[nt] = c2[nt * 16 + col];

    __syncthreads();   // staged weights visible to all waves

    unsigned short* h1w = h1all + wv * (16 * H1STR);

    uint4 af[2][3];
#define PREF(buf, qi_) {                                                      \
        int nidx_ = __shfl(idxAll, (qi_) * 16 + col, 64);                     \
        const uint4* rp_ = fx4 + (rowb + nidx_) * 9;                          \
        af[buf][0] = rp_[quad];                                               \
        af[buf][1] = rp_[4 + quad];                                           \
        uint4 f2_ = rp_[8];                                                   \
        af[buf][2] = (quad == 0) ? f2_ : make_uint4(0u, 0u, 0u, 0u); }

    PREF(0, 0);

#pragma unroll
    for (int qi = 0; qi < 4; ++qi) {
        const int cur = qi & 1;
        // GEMM1: A = gathered rows (regs), B = w1a (LDS), acc init = qterm + c1
        f32x4 acc1[4];
#pragma unroll
        for (int nt = 0; nt < 4; ++nt)
            acc1[nt] = (f32x4){qcc[qi][nt], qcc[qi][nt], qcc[qi][nt], qcc[qi][nt]};
#pragma unroll
        for (int ks = 0; ks < 3; ++ks) {
            s16x8 a = as8(af[cur][ks]);
#pragma unroll
            for (int nt = 0; nt < 4; ++nt) {
                s16x8 bfr = *(const s16x8*)(w1a + (nt * 16 + col) * 104 + ks * 32 + quad * 8);
                acc1[nt] = __builtin_amdgcn_mfma_f32_16x16x32_bf16(a, bfr, acc1[nt], 0, 0, 0);
            }
        }
        // kick next query's gather while h1/GEMM2 run
        if (qi < 3) PREF(cur ^ 1, qi + 1);
        // h1 = relu(acc1) -> LDS (wave-private; stride 76 -> 32-bank writes)
#pragma unroll
        for (int nt = 0; nt < 4; ++nt)
#pragma unroll
            for (int rr = 0; rr < 4; ++rr)
                h1w[(quad * 4 + rr) * H1STR + nt * 16 + col] = bf16b(fmaxf(acc1[nt][rr], 0.f));
        LDS_FENCE();
        // GEMM2 + maxpool, A-fragments hoisted (identical for both halves)
        s16x8 a2f[2];
        a2f[0] = *(const s16x8*)(h1w + col * H1STR + quad * 8);
        a2f[1] = *(const s16x8*)(h1w + col * H1STR + 32 + quad * 8);
#pragma unroll
        for (int hf = 0; hf < 2; ++hf) {
            f32x4 acc2[4];
#pragma unroll
            for (int nt = 0; nt < 4; ++nt) acc2[nt] = (f32x4){0.f, 0.f, 0.f, 0.f};
#pragma unroll
            for (int ks = 0; ks < 2; ++ks) {
#pragma unroll
                for (int nt = 0; nt < 4; ++nt) {
                    s16x8 wf = *(const s16x8*)(w2l + ((hf * 4 + nt) * 16 + col) * 88 + ks * 32 + quad * 8);
                    acc2[nt] = __builtin_amdgcn_mfma_f32_16x16x32_bf16(a2f[ks], wf, acc2[nt], 0, 0, 0);
                }
            }
#pragma unroll
            for (int nt = 0; nt < 4; ++nt) {
                float m0 = fmaxf(fmaxf(acc2[nt][0], acc2[nt][1]), fmaxf(acc2[nt][2], acc2[nt][3]));
                m0 = fmaxf(m0 + c2v[hf * 4 + nt], 0.f);
                m0 = fmaxf(m0, __shfl_xor(m0, 16, 64));
                m0 = fmaxf(m0, __shfl_xor(m0, 32, 64));
                if (quad == 0)
                    otile[(wv * 4 + qi) * 130 + (hf * 4 + nt) * 16 + col] = m0;
            }
        }
        LDS_FENCE();   // drain h1 reads before next iteration's overwrite
    }
    __syncthreads();
    // coalesced store: consecutive threads -> consecutive q, same channel
    for (int i = threadIdx.x; i < H2 * 64; i += 1024) {
        int ch = i >> 6, q = i & 63;
        out1[((size_t)(b * H2 + ch)) * PP + q0base + q] = otile[q * 130 + ch];
    }
#undef PREF
}

extern "C" void kernel_launch(void* const* d_in, const int* in_sizes, int n_in,
                              void* d_out, int out_size, void* d_ws, size_t ws_size,
                              hipStream_t stream) {
    const float* xyz  = (const float*)d_in[0];
    const float* feat = (const float*)d_in[1];
    const float* W1   = (const float*)d_in[2];
    const float* b1   = (const float*)d_in[3];
    const float* g1   = (const float*)d_in[4];
    const float* be1  = (const float*)d_in[5];
    const float* m1   = (const float*)d_in[6];
    const float* v1   = (const float*)d_in[7];
    const float* W2   = (const float*)d_in[8];
    const float* b2   = (const float*)d_in[9];
    const float* g2   = (const float*)d_in[10];
    const float* be2  = (const float*)d_in[11];
    const float* m2   = (const float*)d_in[12];
    const float* v2   = (const float*)d_in[13];

    char* ws = (char*)d_ws;
    unsigned*       fxtb = (unsigned*)(ws + OFF_FXT);
    float4*         pts4 = (float4*)(ws + OFF_PTS4);
    unsigned short* w1p  = (unsigned short*)(ws + OFF_W1P);
    unsigned short* w2p  = (unsigned short*)(ws + OFF_W2P);
    float*          c1   = (float*)(ws + OFF_C1);
    float*          c2   = (float*)(ws + OFF_C2);
    unsigned*       flg  = (unsigned*)(ws + OFF_FLG);

    float* out0 = (float*)d_out;
    float* out1 = out0 + (size_t)BB * PP * 3;
    float* out2 = out1 + (size_t)BB * H2 * PP;

    hipLaunchKernelGGL(kfused, dim3(256), dim3(1024), 0, stream,
                       xyz, feat, W1, b1, g1, be1, m1, v1,
                       W2, b2, g2, be2, m2, v2,
                       fxtb, pts4, w1p, w2p, c1, c2, flg,
                       out0, out1, out2);
}

// Round 6
// 181.974 us; speedup vs baseline: 1.9590x; 1.9590x over previous
//
#include <hip/hip_runtime.h>
#include <hip/hip_bf16.h>

// Problem constants
#define BB 8
#define NN 8192
#define CC 64
#define PP 2048
#define KK 16
#define H1 64
#define H2 128
#define H1STR 76                        // h1 row stride (shorts): 32-bank-spread writes

typedef float  f32x4 __attribute__((ext_vector_type(4)));
typedef short  s16x8 __attribute__((ext_vector_type(8)));

// ---- workspace layout (bytes) ----
#define OFF_FXT   0u                    // B*N rows of 72 bf16 = 9,437,184
#define OFF_PTS4  17825792u             // B*N float4 = 2,097,152
#define OFF_W1P   20971520u             // 64*192 bf16 ([n][0:96)=W1a*s, [n][96:192)=(W1b-W1a)*s)
#define OFF_W2P   20996096u             // 128*72 bf16
#define OFF_C1    21014528u             // 64 f32
#define OFF_C2    21014784u             // 128 f32
#define OFF_FLGP  21016576u             // 256 u32: pts4-ready flags
#define OFF_FLGF  21017600u             // 256 u32: fxtb+fold-ready flags

#define FLTMAX 3.402823466e+38f
#define MAGIC 0x9E3779B1u

static __device__ __forceinline__ unsigned short bf16b(float v) {
    __hip_bfloat16 h = __float2bfloat16(v);
    return *reinterpret_cast<unsigned short*>(&h);
}
static __device__ __forceinline__ unsigned pk2(float a, float b) {
    return ((unsigned)bf16b(b) << 16) | (unsigned)bf16b(a);
}
static __device__ __forceinline__ s16x8 as8(uint4 v) {
    union { uint4 u; s16x8 s; } x; x.u = v; return x.s;
}
// wave-local LDS fence: compiler barrier + LDS drain, NO vmcnt drain
#define LDS_FENCE() asm volatile("s_waitcnt lgkmcnt(0)" ::: "memory")

// ---------------- single kernel, flag-synced (no cooperative launch) ----
// 256 blocks x 1024 thr = 1 block/CU -> all blocks co-resident by capacity.
// r5 lesson: ALL waves spinning on agent-scope acquire loads starves the
// flag writes (280us). Fix: ONE wave polls per block + s_sleep, others park
// at __syncthreads. pts4 is produced EARLY (wave 0, xyz-only) so flagP is
// set ~2us in; Phase A's wait finds it already satisfied. b = blockIdx&7
// pins batch -> XCD: pts4/fxtb written and read on the same XCD L2.
__global__ __launch_bounds__(1024, 1) void kfused(
    const float* __restrict__ xyz,  const float* __restrict__ feat,
    const float* __restrict__ W1,   const float* __restrict__ b1,
    const float* __restrict__ g1,   const float* __restrict__ be1,
    const float* __restrict__ m1,   const float* __restrict__ v1,
    const float* __restrict__ W2,   const float* __restrict__ b2,
    const float* __restrict__ g2,   const float* __restrict__ be2,
    const float* __restrict__ m2,   const float* __restrict__ v2,
    unsigned* __restrict__ fxtb,    float4* __restrict__ pts4,
    unsigned short* __restrict__ w1p, unsigned short* __restrict__ w2p,
    float* __restrict__ c1,         float* __restrict__ c2,
    unsigned* __restrict__ flagP,   unsigned* __restrict__ flagF,
    float* __restrict__ out0, float* __restrict__ out1, float* __restrict__ out2) {

    __shared__ __align__(16) char smem[131072];
    __shared__ float2 scratch[16][2][64];    // 16 KB dual per-wave buffers
    __shared__ int knnl[16][64];             // 4 KB: per-wave [4 queries][16 ranks]
    int lane = threadIdx.x & 63;
    int wv   = threadIdx.x >> 6;
    int b    = blockIdx.x & 7;               // XCD-aware batch assignment
    int g    = blockIdx.x >> 3;              // query-group 0..31
    int q0base = g * 64;
    size_t pb = (size_t)b * NN;

    // ---- early pts4 (wave 0 only; needs just xyz) + flagP release ----
    if (wv == 0) {
#pragma unroll
        for (int i = 0; i < 4; ++i) {
            int n = g * 256 + i * 64 + lane;
            const float* pp = xyz + (pb + n) * 3;
            float x = pp[0], y = pp[1], z = pp[2];
            pts4[pb + n] = make_float4(x, y, z, x * x + y * y + z * z);
        }
        asm volatile("s_waitcnt vmcnt(0)" ::: "memory");   // wave's stores drained
        if (lane == 0)
            __hip_atomic_store(flagP + blockIdx.x, MAGIC,
                               __ATOMIC_RELEASE, __HIP_MEMORY_SCOPE_AGENT);
    }

    // ================= Phase T: transpose 4 tiles -> fxtb, fold ===========
    {
        float (*tile)[72][65] = (float (*)[72][65])smem;   // 74,880 B
        int grp = threadIdx.x >> 8;          // 0..3 (one 64-pt tile each)
        int t256 = threadIdx.x & 255;
        int tx = t256 & 63, ty = t256 >> 6;  // ty 0..3
        int n0 = (g * 4 + grp) * 64;
        for (int c = ty; c < 72; c += 4) {
            float v;
            if (c < 64)       v = feat[((size_t)b * 64 + c) * NN + n0 + tx];
            else if (c < 67)  v = xyz[((size_t)b * NN + n0 + tx) * 3 + (c - 64)];
            else              v = 0.f;                 // pad cols 67..71
            tile[grp][c][tx] = v;
        }
        // weight fold slice (21,696 elems over 256 blocks), hidden in T latency
        if (threadIdx.x < 85) {
            int i = blockIdx.x * 85 + threadIdx.x;
            if (i < 6144) {                      // W1a folded: [64][96]
                int n = i / 96, c = i - n * 96;
                float s = g1[n] * rsqrtf(v1[n] + 1e-5f);
                w1p[n * 192 + c] = bf16b((c < 67) ? W1[n * 134 + c] * s : 0.f);
            } else if (i < 12288) {              // W1d = (W1b-W1a)*s at +96
                int j = i - 6144;
                int n = j / 96, c = j - n * 96;
                float s = g1[n] * rsqrtf(v1[n] + 1e-5f);
                w1p[n * 192 + 96 + c] =
                    bf16b((c < 67) ? (W1[n * 134 + 67 + c] - W1[n * 134 + c]) * s : 0.f);
            } else if (i < 21504) {              // W2 folded: [128][72]
                int j = i - 12288;
                int o = j / 72, k = j - o * 72;
                float s = g2[o] * rsqrtf(v2[o] + 1e-5f);
                w2p[j] = bf16b((k < 64) ? W2[o * 64 + k] * s : 0.f);
            } else if (i < 21568) {
                int l = i - 21504;
                float s = g1[l] * rsqrtf(v1[l] + 1e-5f);
                c1[l] = s * (b1[l] - m1[l]) + be1[l];
            } else if (i < 21696) {
                int p = i - 21568;
                float s = g2[p] * rsqrtf(v2[p] + 1e-5f);
                c2[p] = s * (b2[p] - m2[p]) + be2[p];
            }
        }
        __syncthreads();
        size_t base = ((size_t)b * NN + n0) * 36;   // 36 dwords (72 bf16) per row
        for (int e = t256; e < 64 * 36; e += 256) {
            int nl = e / 36, c = e - nl * 36;
            fxtb[base + e] = pk2(tile[grp][2 * c][nl], tile[grp][2 * c + 1][nl]);
        }
        if (n0 < PP) {
            if (t256 < 64)
                out2[b * PP + n0 + t256] = (float)(n0 + t256);
            for (int e = t256; e < 64 * 3; e += 256) {
                int nl = e / 3, d = e - nl * 3;
                out0[((size_t)b * PP + n0 + nl) * 3 + d] = tile[grp][64 + d][nl];
            }
        }
        __syncthreads();   // tile dead (stage overlay safe) + all stores drained
        if (threadIdx.x == 0) {
            __threadfence();             // device-scope release of fxtb/fold
            __hip_atomic_store(flagF + blockIdx.x, MAGIC,
                               __ATOMIC_RELEASE, __HIP_MEMORY_SCOPE_AGENT);
        }
    }

    // wait for this batch's 32 pts4 producers: ONE wave polls, others park
    if (wv == 0) {
        for (;;) {
            unsigned v = MAGIC;
            if (lane < 32)
                v = __hip_atomic_load(flagP + (lane * 8 + b),
                                      __ATOMIC_ACQUIRE, __HIP_MEMORY_SCOPE_AGENT);
            if (__all(v == MAGIC)) break;
            __builtin_amdgcn_s_sleep(8);
        }
    }
    __syncthreads();

    // ================= Phase A: KNN =================
    {
        float4* stage = (float4*)smem;       // swizzled slot(r,c)=r*64+((c+(r>>1))&63)
        int q0 = q0base + wv * 4;

        float4 qc = make_float4(0.f, 0.f, 0.f, 0.f);
        if (lane < 4) qc = pts4[pb + q0 + lane];
        float qx2 = -2.f * qc.x, qy2 = -2.f * qc.y, qz2 = -2.f * qc.z;
        float bx[4], by[4], bz[4];
#pragma unroll
        for (int q = 0; q < 4; ++q) {
            bx[q] = __shfl(qx2, q); by[q] = __shfl(qy2, q); bz[q] = __shfl(qz2, q);
        }

        // stage all 8192 points (coalesced b128 from pts4, same-XCD L2)
#pragma unroll
        for (int i = 0; i < 8; ++i) {
            int p = i * 1024 + threadIdx.x;
            float4 v = pts4[pb + p];
            int r = p >> 6, c = p & 63;
            stage[(r << 6) | ((c + (r >> 1)) & 63)] = v;
        }
        __syncthreads();

        // Phase 1: per-lane min over its 128 candidates (rows 2L, 2L+1)
        float m[4];
#pragma unroll
        for (int q = 0; q < 4; ++q) m[q] = FLTMAX;
#pragma unroll
        for (int rr = 0; rr < 2; ++rr) {
            int rowbase = (2 * lane + rr) << 6;
#pragma unroll
            for (int j8 = 0; j8 < 8; ++j8) {
                float4 cc[8];
#pragma unroll
                for (int i = 0; i < 8; ++i)
                    cc[i] = stage[rowbase | ((j8 * 8 + i + lane) & 63)];
#pragma unroll
                for (int q = 0; q < 4; ++q) {
                    float x = bx[q], y = by[q], z = bz[q];
#pragma unroll
                    for (int i = 0; i < 8; i += 2) {
                        float e0 = fmaf(z, cc[i].z, fmaf(y, cc[i].y, fmaf(x, cc[i].x, cc[i].w)));
                        float e1 = fmaf(z, cc[i+1].z, fmaf(y, cc[i+1].y, fmaf(x, cc[i+1].x, cc[i+1].w)));
                        m[q] = fminf(fminf(m[q], e0), e1);
                    }
                }
            }
        }

        // Interleaved threshold sorts: T[q] = 16th smallest of 64 lane-mins
        float sv0 = m[0], sv1 = m[1], sv2 = m[2], sv3 = m[3];
#pragma unroll
        for (int k = 2; k <= 64; k <<= 1) {
#pragma unroll
            for (int j = k >> 1; j > 0; j >>= 1) {
                bool keepMin = (((lane & k) == 0) == ((lane & j) == 0));
                float p0 = __shfl_xor(sv0, j, 64);
                float p1 = __shfl_xor(sv1, j, 64);
                float p2 = __shfl_xor(sv2, j, 64);
                float p3 = __shfl_xor(sv3, j, 64);
                sv0 = keepMin ? fminf(sv0, p0) : fmaxf(sv0, p0);
                sv1 = keepMin ? fminf(sv1, p1) : fmaxf(sv1, p1);
                sv2 = keepMin ? fminf(sv2, p2) : fmaxf(sv2, p2);
                sv3 = keepMin ? fminf(sv3, p3) : fmaxf(sv3, p3);
            }
        }
        float T[4];
        T[0] = __shfl(sv0, 15, 64); T[1] = __shfl(sv1, 15, 64);
        T[2] = __shfl(sv2, 15, 64); T[3] = __shfl(sv3, 15, 64);

        unsigned long long below = (lane == 63) ? 0x7FFFFFFFFFFFFFFFull
                                                : ((1ull << lane) - 1ull);
#pragma unroll
        for (int pr = 0; pr < 4; pr += 2) {
            int Ms[2];
#pragma unroll
            for (int u = 0; u < 2; ++u) {
                int q = pr + u;
                float x = bx[q], y = by[q], z = bz[q], tq = T[q];
                unsigned long long rm = __ballot(m[q] <= tq);
                int cnt = 0;
                while (rm) {
                    int sl = __ffsll((long long)rm) - 1; rm &= rm - 1;
                    int phys = (lane + sl) & 63;
                    float4 c0 = stage[((2 * sl) << 6) | phys];
                    float4 c1v_ = stage[((2 * sl + 1) << 6) | phys];
                    float e0 = fmaf(z, c0.z, fmaf(y, c0.y, fmaf(x, c0.x, c0.w)));
                    float e1 = fmaf(z, c1v_.z, fmaf(y, c1v_.y, fmaf(x, c1v_.x, c1v_.w)));
                    unsigned long long b0 = __ballot(e0 <= tq);
                    if (e0 <= tq) {
                        int pos = cnt + __popcll(b0 & below);
                        if (pos < 64)
                            scratch[wv][u][pos] = make_float2(e0, __int_as_float(sl * 128 + lane));
                    }
                    cnt += __popcll(b0);
                    unsigned long long b1 = __ballot(e1 <= tq);
                    if (e1 <= tq) {
                        int pos = cnt + __popcll(b1 & below);
                        if (pos < 64)
                            scratch[wv][u][pos] = make_float2(e1, __int_as_float(sl * 128 + 64 + lane));
                    }
                    cnt += __popcll(b1);
                }
                Ms[u] = min(cnt, 64);
            }
            LDS_FENCE();   // drain compaction writes before readback
#pragma unroll
            for (int u = 0; u < 2; ++u) {
                int M = Ms[u];
                float2 own = scratch[wv][u][lane];
                float di = own.x; int ni = __float_as_int(own.y);
                int rank = 0;
                const float2* buf = &scratch[wv][u][0];
#pragma unroll 4
                for (int j = 0; j < M; ++j) {
                    float2 e = buf[j];
                    int nj = __float_as_int(e.y);
                    rank += (e.x < di || (e.x == di && nj < ni)) ? 1 : 0;
                }
                if (lane < M && rank < 16)
                    knnl[wv][(pr + u) * 16 + rank] = ni;   // LDS, not global
            }
            LDS_FENCE();   // order scratch reuse across pairs
        }
    }

    // all 64 knn indices for this wave's 4 queries (wave-local LDS)
    int idxAll = knnl[wv][lane];

    __syncthreads();   // stage buffer dead -> safe to overlay

    // wait for ALL 256 flagF (fxtb of every batch + full weight fold):
    // ONE wave polls, others park (by now long since satisfied)
    if (wv == 0) {
        for (;;) {
            unsigned v0 = __hip_atomic_load(flagF + lane,       __ATOMIC_ACQUIRE, __HIP_MEMORY_SCOPE_AGENT);
            unsigned v1 = __hip_atomic_load(flagF + 64 + lane,  __ATOMIC_ACQUIRE, __HIP_MEMORY_SCOPE_AGENT);
            unsigned v2_ = __hip_atomic_load(flagF + 128 + lane, __ATOMIC_ACQUIRE, __HIP_MEMORY_SCOPE_AGENT);
            unsigned v3 = __hip_atomic_load(flagF + 192 + lane, __ATOMIC_ACQUIRE, __HIP_MEMORY_SCOPE_AGENT);
            if (__all(v0 == MAGIC && v1 == MAGIC && v2_ == MAGIC && v3 == MAGIC)) break;
            __builtin_amdgcn_s_sleep(8);
        }
    }
    __syncthreads();

    // ================= Phase B: MLP =================
    unsigned short* w1a   = (unsigned short*)smem;             // [64][104]
    unsigned short* h1all = (unsigned short*)(smem + 13312);   // 16 x [16][H1STR]
    unsigned short* w2l   = (unsigned short*)(smem + 52224);   // [128][88]
    float*          otile = (float*)(smem + 74752);            // [64][130]
    int col = lane & 15, quad = lane >> 4;
    const uint4* fx4 = (const uint4*)fxtb;
    size_t rowb = (size_t)b * NN;

    // stage weights into LDS (all 1024 threads)
    {
        const unsigned* src1 = (const unsigned*)w1p;   // rows: 96 dw stride
        unsigned* d1 = (unsigned*)w1a;
        for (int t = threadIdx.x; t < 64 * 48; t += 1024) {
            int r = t / 48, c = t - r * 48;
            d1[r * 52 + c] = src1[r * 96 + c];
        }
        const unsigned* src2 = (const unsigned*)w2p;   // rows: 36 dw
        unsigned* d2 = (unsigned*)w2l;
        for (int t = threadIdx.x; t < 128 * 36; t += 1024) {
            int r = t / 36, c = t - r * 36;
            d2[r * 44 + c] = src2[r * 36 + c];
        }
    }

    // qterm: f_q . W1d for this wave's 4 queries (W1d fragments from global)
    f32x4 accq[4];
#pragma unroll
    for (int nt = 0; nt < 4; ++nt) accq[nt] = (f32x4){0.f, 0.f, 0.f, 0.f};
    {
        const uint4* rp = fx4 + (rowb + q0base + wv * 4 + col) * 9;
        uint4 qf0 = rp[quad];
        uint4 qf1 = rp[4 + quad];
        uint4 qf2 = rp[8];
        if (quad != 0) qf2 = make_uint4(0u, 0u, 0u, 0u);
        uint4 qf[3] = {qf0, qf1, qf2};
#pragma unroll
        for (int ks = 0; ks < 3; ++ks) {
            s16x8 a = as8(qf[ks]);
#pragma unroll
            for (int nt = 0; nt < 4; ++nt) {
                s16x8 bfr = *(const s16x8*)(w1p + (nt * 16 + col) * 192 + 96 + ks * 32 + quad * 8);
                accq[nt] = __builtin_amdgcn_mfma_f32_16x16x32_bf16(a, bfr, accq[nt], 0, 0, 0);
            }
        }
    }
    float qcc[4][4];   // qterm + c1, per (query, nt)
    {
        float c1v[4];
#pragma unroll
        for (int nt = 0; nt < 4; ++nt) c1v[nt] = c1[nt * 16 + col];
#pragma unroll
        for (int qi = 0; qi < 4; ++qi)
#pragma unroll
            for (int nt = 0; nt < 4; ++nt)
                qcc[qi][nt] = __shfl(accq[nt][qi], col, 64) + c1v[nt];
    }
    float c2v[8];
#pragma unroll
    for (int nt = 0; nt < 8; ++nt) c2v[nt] = c2[nt * 16 + col];

    __syncthreads();   // staged weights visible to all waves

    unsigned short* h1w = h1all + wv * (16 * H1STR);

    uint4 af[2][3];
#define PREF(buf, qi_) {                                                      \
        int nidx_ = __shfl(idxAll, (qi_) * 16 + col, 64);                     \
        const uint4* rp_ = fx4 + (rowb + nidx_) * 9;                          \
        af[buf][0] = rp_[quad];                                               \
        af[buf][1] = rp_[4 + quad];                                           \
        uint4 f2_ = rp_[8];                                                   \
        af[buf][2] = (quad == 0) ? f2_ : make_uint4(0u, 0u, 0u, 0u); }

    PREF(0, 0);

#pragma unroll
    for (int qi = 0; qi < 4; ++qi) {
        const int cur = qi & 1;
        // GEMM1: A = gathered rows (regs), B = w1a (LDS), acc init = qterm + c1
        f32x4 acc1[4];
#pragma unroll
        for (int nt = 0; nt < 4; ++nt)
            acc1[nt] = (f32x4){qcc[qi][nt], qcc[qi][nt], qcc[qi][nt], qcc[qi][nt]};
#pragma unroll
        for (int ks = 0; ks < 3; ++ks) {
            s16x8 a = as8(af[cur][ks]);
#pragma unroll
            for (int nt = 0; nt < 4; ++nt) {
                s16x8 bfr = *(const s16x8*)(w1a + (nt * 16 + col) * 104 + ks * 32 + quad * 8);
                acc1[nt] = __builtin_amdgcn_mfma_f32_16x16x32_bf16(a, bfr, acc1[nt], 0, 0, 0);
            }
        }
        // kick next query's gather while h1/GEMM2 run
        if (qi < 3) PREF(cur ^ 1, qi + 1);
        // h1 = relu(acc1) -> LDS (wave-private; stride 76 -> 32-bank writes)
#pragma unroll
        for (int nt = 0; nt < 4; ++nt)
#pragma unroll
            for (int rr = 0; rr < 4; ++rr)
                h1w[(quad * 4 + rr) * H1STR + nt * 16 + col] = bf16b(fmaxf(acc1[nt][rr], 0.f));
        LDS_FENCE();
        // GEMM2 + maxpool, A-fragments hoisted (identical for both halves)
        s16x8 a2f[2];
        a2f[0] = *(const s16x8*)(h1w + col * H1STR + quad * 8);
        a2f[1] = *(const s16x8*)(h1w + col * H1STR + 32 + quad * 8);
#pragma unroll
        for (int hf = 0; hf < 2; ++hf) {
            f32x4 acc2[4];
#pragma unroll
            for (int nt = 0; nt < 4; ++nt) acc2[nt] = (f32x4){0.f, 0.f, 0.f, 0.f};
#pragma unroll
            for (int ks = 0; ks < 2; ++ks) {
#pragma unroll
                for (int nt = 0; nt < 4; ++nt) {
                    s16x8 wf = *(const s16x8*)(w2l + ((hf * 4 + nt) * 16 + col) * 88 + ks * 32 + quad * 8);
                    acc2[nt] = __builtin_amdgcn_mfma_f32_16x16x32_bf16(a2f[ks], wf, acc2[nt], 0, 0, 0);
                }
            }
#pragma unroll
            for (int nt = 0; nt < 4; ++nt) {
                float m0 = fmaxf(fmaxf(acc2[nt][0], acc2[nt][1]), fmaxf(acc2[nt][2], acc2[nt][3]));
                m0 = fmaxf(m0 + c2v[hf * 4 + nt], 0.f);
                m0 = fmaxf(m0, __shfl_xor(m0, 16, 64));
                m0 = fmaxf(m0, __shfl_xor(m0, 32, 64));
                if (quad == 0)
                    otile[(wv * 4 + qi) * 130 + (hf * 4 + nt) * 16 + col] = m0;
            }
        }
        LDS_FENCE();   // drain h1 reads before next iteration's overwrite
    }
    __syncthreads();
    // coalesced store: consecutive threads -> consecutive q, same channel
    for (int i = threadIdx.x; i < H2 * 64; i += 1024) {
        int ch = i >> 6, q = i & 63;
        out1[((size_t)(b * H2 + ch)) * PP + q0base + q] = otile[q * 130 + ch];
    }
#undef PREF
}

extern "C" void kernel_launch(void* const* d_in, const int* in_sizes, int n_in,
                              void* d_out, int out_size, void* d_ws, size_t ws_size,
                              hipStream_t stream) {
    const float* xyz  = (const float*)d_in[0];
    const float* feat = (const float*)d_in[1];
    const float* W1   = (const float*)d_in[2];
    const float* b1   = (const float*)d_in[3];
    const float* g1   = (const float*)d_in[4];
    const float* be1  = (const float*)d_in[5];
    const float* m1   = (const float*)d_in[6];
    const float* v1   = (const float*)d_in[7];
    const float* W2   = (const float*)d_in[8];
    const float* b2   = (const float*)d_in[9];
    const float* g2   = (const float*)d_in[10];
    const float* be2  = (const float*)d_in[11];
    const float* m2   = (const float*)d_in[12];
    const float* v2   = (const float*)d_in[13];

    char* ws = (char*)d_ws;
    unsigned*       fxtb = (unsigned*)(ws + OFF_FXT);
    float4*         pts4 = (float4*)(ws + OFF_PTS4);
    unsigned short* w1p  = (unsigned short*)(ws + OFF_W1P);
    unsigned short* w2p  = (unsigned short*)(ws + OFF_W2P);
    float*          c1   = (float*)(ws + OFF_C1);
    float*          c2   = (float*)(ws + OFF_C2);
    unsigned*       flgP = (unsigned*)(ws + OFF_FLGP);
    unsigned*       flgF = (unsigned*)(ws + OFF_FLGF);

    float* out0 = (float*)d_out;
    float* out1 = out0 + (size_t)BB * PP * 3;
    float* out2 = out1 + (size_t)BB * H2 * PP;

    hipLaunchKernelGGL(kfused, dim3(256), dim3(1024), 0, stream,
                       xyz, feat, W1, b1, g1, be1, m1, v1,
                       W2, b2, g2, be2, m2, v2,
                       fxtb, pts4, w1p, w2p, c1, c2, flgP, flgF,
                       out0, out1, out2);
}

// Round 7
// 161.345 us; speedup vs baseline: 2.2094x; 1.1279x over previous
//
#include <hip/hip_runtime.h>
#include <hip/hip_bf16.h>

// Problem constants
#define BB 8
#define NN 8192
#define CC 64
#define PP 2048
#define KK 16
#define H1 64
#define H2 128
#define H1STR 76                        // h1 row stride (shorts): 32-bank-spread writes

typedef float  f32x4 __attribute__((ext_vector_type(4)));
typedef float  f32x2 __attribute__((ext_vector_type(2)));
typedef short  s16x8 __attribute__((ext_vector_type(8)));

// ---- workspace layout (bytes) ----
#define OFF_FXT   0u                    // B*N rows of 72 bf16 = 9,437,184
#define OFF_PTS4  17825792u             // B*N float4 = 2,097,152
#define OFF_W1P   20971520u             // 64*192 bf16 ([n][0:96)=W1a*s, [n][96:192)=(W1b-W1a)*s)
#define OFF_W2P   20996096u             // 128*72 bf16
#define OFF_C1    21014528u             // 64 f32
#define OFF_C2    21014784u             // 128 f32

#define FLTMAX 3.402823466e+38f

static __device__ __forceinline__ unsigned short bf16b(float v) {
    __hip_bfloat16 h = __float2bfloat16(v);
    return *reinterpret_cast<unsigned short*>(&h);
}
static __device__ __forceinline__ unsigned pk2(float a, float b) {
    return ((unsigned)bf16b(b) << 16) | (unsigned)bf16b(a);
}
static __device__ __forceinline__ s16x8 as8(uint4 v) {
    union { uint4 u; s16x8 s; } x; x.u = v; return x.s;
}
// wave-local LDS fence: compiler barrier + LDS drain, NO vmcnt drain
#define LDS_FENCE() asm volatile("s_waitcnt lgkmcnt(0)" ::: "memory")

// ---------------- K1: transpose feat -> fxtb, pts4, outs, weight fold ----
__global__ __launch_bounds__(512) void k1_prep(const float* __restrict__ xyz,
                                               const float* __restrict__ feat,
                                               unsigned* __restrict__ fxtb,
                                               float4* __restrict__ pts4,
                                               float* __restrict__ out0,
                                               float* __restrict__ out2,
                                               const float* __restrict__ W1, const float* __restrict__ b1,
                                               const float* __restrict__ g1, const float* __restrict__ be1,
                                               const float* __restrict__ m1, const float* __restrict__ v1,
                                               const float* __restrict__ W2, const float* __restrict__ b2,
                                               const float* __restrict__ g2, const float* __restrict__ be2,
                                               const float* __restrict__ m2, const float* __restrict__ v2,
                                               unsigned short* __restrict__ w1p,
                                               unsigned short* __restrict__ w2p,
                                               float* __restrict__ c1, float* __restrict__ c2) {
    __shared__ float tile[72][65];
    // weight fold slice (21,696 elems over blocks 0..255), hidden in k1 latency
    if (blockIdx.x < 256 && threadIdx.x < 85) {
        int i = blockIdx.x * 85 + threadIdx.x;
        if (i < 6144) {                      // W1a folded: [64][96]
            int n = i / 96, c = i - n * 96;
            float s = g1[n] * rsqrtf(v1[n] + 1e-5f);
            w1p[n * 192 + c] = bf16b((c < 67) ? W1[n * 134 + c] * s : 0.f);
        } else if (i < 12288) {              // W1d = (W1b-W1a)*s: [64][96] at +96
            int j = i - 6144;
            int n = j / 96, c = j - n * 96;
            float s = g1[n] * rsqrtf(v1[n] + 1e-5f);
            w1p[n * 192 + 96 + c] =
                bf16b((c < 67) ? (W1[n * 134 + 67 + c] - W1[n * 134 + c]) * s : 0.f);
        } else if (i < 21504) {              // W2 folded: [128][72]
            int j = i - 12288;
            int o = j / 72, k = j - o * 72;
            float s = g2[o] * rsqrtf(v2[o] + 1e-5f);
            w2p[j] = bf16b((k < 64) ? W2[o * 64 + k] * s : 0.f);
        } else if (i < 21568) {
            int l = i - 21504;
            float s = g1[l] * rsqrtf(v1[l] + 1e-5f);
            c1[l] = s * (b1[l] - m1[l]) + be1[l];
        } else if (i < 21696) {
            int p = i - 21568;
            float s = g2[p] * rsqrtf(v2[p] + 1e-5f);
            c2[p] = s * (b2[p] - m2[p]) + be2[p];
        }
    }
    int b  = blockIdx.x >> 7;
    int n0 = (blockIdx.x & 127) * 64;
    int tx = threadIdx.x & 63, ty = threadIdx.x >> 6;
    for (int c = ty; c < 72; c += 8) {
        float v;
        if (c < 64)       v = feat[((size_t)b * 64 + c) * NN + n0 + tx];
        else if (c < 67)  v = xyz[((size_t)b * NN + n0 + tx) * 3 + (c - 64)];
        else              v = 0.f;                 // pad cols 67..71
        tile[c][tx] = v;
    }
    __syncthreads();
    size_t base = ((size_t)b * NN + n0) * 36;      // 36 dwords (72 bf16) per row
    for (int e = threadIdx.x; e < 64 * 36; e += 512) {
        int nl = e / 36, c = e - nl * 36;
        fxtb[base + e] = pk2(tile[2 * c][nl], tile[2 * c + 1][nl]);
    }
    if (threadIdx.x < 64) {
        int n = n0 + threadIdx.x;
        float x = tile[64][threadIdx.x], y = tile[65][threadIdx.x], z = tile[66][threadIdx.x];
        pts4[(size_t)b * NN + n] = make_float4(x, y, z, x * x + y * y + z * z);
        if (n0 < PP) out2[b * PP + n] = (float)n;
    }
    if (n0 < PP) {
        for (int e = threadIdx.x; e < 64 * 3; e += 512) {
            int nl = e / 3, d = e - nl * 3;
            out0[((size_t)b * PP + n0 + nl) * 3 + d] = tile[64 + d][nl];
        }
    }
}

// ---------------- K23: fused KNN + MLP (r3 structure, packed-f32 KNN) ----
// 256 blocks x 1024 thr, 1 block/CU. r4-r6 lesson: whole-pipeline fusion
// (cooperative or flag-synced) never beats this two-kernel form -> keep it.
// NEW: distance pass uses v_pk_fma_f32 (CDNA dual-f32) + v_min3_f32 on a
// pair-SoA stage: pair k = points (2k*64+c, (2k+1)*64+c);
//   stageA[slot] = (x0,x1,y0,y1), stageB[slot] = (z0,z1,w0,w1),
//   slot(r,c) = r*64 + ((c+r)&63)  (same bank-class family as r3's swizzle).
// Lane owns pair-row r = lane (same 128 candidates as before); fma order
// matches the scalar version exactly -> identical KNN selection.
__global__ __launch_bounds__(1024, 1) void k23(const float4* __restrict__ pts4,
                                               const unsigned* __restrict__ fxtb,
                                               const unsigned short* __restrict__ w1p,
                                               const unsigned short* __restrict__ w2p,
                                               const float* __restrict__ c1,
                                               const float* __restrict__ c2,
                                               float* __restrict__ out1) {
    __shared__ __align__(16) char smem[131072];
    __shared__ float2 scratch[16][2][64];    // 16 KB dual per-wave buffers
    __shared__ int knnl[16][64];             // 4 KB: per-wave [4 queries][16 ranks]
    int lane = threadIdx.x & 63;
    int wv   = threadIdx.x >> 6;
    int b    = blockIdx.x & 7;               // XCD-aware batch assignment
    int q0base = (blockIdx.x >> 3) * 64;
    size_t pb = (size_t)b * NN;

    // ================= Phase A: KNN =================
    {
        float4* stageA = (float4*)smem;                  // 4096 float4 = 64 KB
        float4* stageB = (float4*)(smem + 65536);        // 64 KB
        int q0 = q0base + wv * 4;

        float4 qc = make_float4(0.f, 0.f, 0.f, 0.f);
        if (lane < 4) qc = pts4[pb + q0 + lane];
        float qx2 = -2.f * qc.x, qy2 = -2.f * qc.y, qz2 = -2.f * qc.z;
        float bx[4], by[4], bz[4];
#pragma unroll
        for (int q = 0; q < 4; ++q) {
            bx[q] = __shfl(qx2, q); by[q] = __shfl(qy2, q); bz[q] = __shfl(qz2, q);
        }

        // stage 4096 pairs in SoA form (two coalesced 1KB segments per wave)
#pragma unroll
        for (int i = 0; i < 4; ++i) {
            int p = i * 1024 + threadIdx.x;      // pair id
            int r = p >> 6, c = p & 63;          // c == lane
            float4 e0 = pts4[pb + r * 128 + c];
            float4 e1 = pts4[pb + r * 128 + 64 + c];
            int s = (r << 6) | ((c + r) & 63);
            stageA[s] = make_float4(e0.x, e1.x, e0.y, e1.y);
            stageB[s] = make_float4(e0.z, e1.z, e0.w, e1.w);
        }
        __syncthreads();

        // Phase 1: per-lane min over its 64 pairs (rows 2L, 2L+1), packed f32
        float m[4];
        f32x2 bx2[4], by2[4], bz2[4];
#pragma unroll
        for (int q = 0; q < 4; ++q) {
            m[q] = FLTMAX;
            bx2[q] = (f32x2){bx[q], bx[q]};
            by2[q] = (f32x2){by[q], by[q]};
            bz2[q] = (f32x2){bz[q], bz[q]};
        }
        int rbase = lane << 6;
#pragma unroll
        for (int jj = 0; jj < 16; ++jj) {
            float4 A[4], Bv[4];
#pragma unroll
            for (int i = 0; i < 4; ++i) {
                int phys = (jj * 4 + i + lane) & 63;
                A[i]  = stageA[rbase | phys];
                Bv[i] = stageB[rbase | phys];
            }
#pragma unroll
            for (int q = 0; q < 4; ++q) {
#pragma unroll
                for (int i = 0; i < 4; ++i) {
                    f32x2 e  = (f32x2){Bv[i].z, Bv[i].w};
                    f32x2 xs = (f32x2){A[i].x, A[i].y};
                    f32x2 ys = (f32x2){A[i].z, A[i].w};
                    f32x2 zs = (f32x2){Bv[i].x, Bv[i].y};
                    asm("v_pk_fma_f32 %0, %1, %2, %0" : "+v"(e) : "v"(bx2[q]), "v"(xs));
                    asm("v_pk_fma_f32 %0, %1, %2, %0" : "+v"(e) : "v"(by2[q]), "v"(ys));
                    asm("v_pk_fma_f32 %0, %1, %2, %0" : "+v"(e) : "v"(bz2[q]), "v"(zs));
                    asm("v_min3_f32 %0, %0, %1, %2" : "+v"(m[q]) : "v"(e.x), "v"(e.y));
                }
            }
        }

        // Interleaved threshold sorts: T[q] = 16th smallest of 64 lane-mins
        float sv0 = m[0], sv1 = m[1], sv2 = m[2], sv3 = m[3];
#pragma unroll
        for (int k = 2; k <= 64; k <<= 1) {
#pragma unroll
            for (int j = k >> 1; j > 0; j >>= 1) {
                bool keepMin = (((lane & k) == 0) == ((lane & j) == 0));
                float p0 = __shfl_xor(sv0, j, 64);
                float p1 = __shfl_xor(sv1, j, 64);
                float p2 = __shfl_xor(sv2, j, 64);
                float p3 = __shfl_xor(sv3, j, 64);
                sv0 = keepMin ? fminf(sv0, p0) : fmaxf(sv0, p0);
                sv1 = keepMin ? fminf(sv1, p1) : fmaxf(sv1, p1);
                sv2 = keepMin ? fminf(sv2, p2) : fmaxf(sv2, p2);
                sv3 = keepMin ? fminf(sv3, p3) : fmaxf(sv3, p3);
            }
        }
        float T[4];
        T[0] = __shfl(sv0, 15, 64); T[1] = __shfl(sv1, 15, 64);
        T[2] = __shfl(sv2, 15, 64); T[3] = __shfl(sv3, 15, 64);

        unsigned long long below = (lane == 63) ? 0x7FFFFFFFFFFFFFFFull
                                                : ((1ull << lane) - 1ull);
#pragma unroll
        for (int pr = 0; pr < 4; pr += 2) {
            int Ms[2];
#pragma unroll
            for (int u = 0; u < 2; ++u) {
                int q = pr + u;
                float x = bx[q], y = by[q], z = bz[q], tq = T[q];
                unsigned long long rm = __ballot(m[q] <= tq);
                int cnt = 0;
                while (rm) {
                    int sl = __ffsll((long long)rm) - 1; rm &= rm - 1;
                    int s = (sl << 6) | ((lane + sl) & 63);
                    float4 A = stageA[s];
                    float4 Bv = stageB[s];
                    float e0 = fmaf(z, Bv.x, fmaf(y, A.z, fmaf(x, A.x, Bv.z)));
                    float e1 = fmaf(z, Bv.y, fmaf(y, A.w, fmaf(x, A.y, Bv.w)));
                    unsigned long long b0 = __ballot(e0 <= tq);
                    if (e0 <= tq) {
                        int pos = cnt + __popcll(b0 & below);
                        if (pos < 64)
                            scratch[wv][u][pos] = make_float2(e0, __int_as_float(sl * 128 + lane));
                    }
                    cnt += __popcll(b0);
                    unsigned long long b1 = __ballot(e1 <= tq);
                    if (e1 <= tq) {
                        int pos = cnt + __popcll(b1 & below);
                        if (pos < 64)
                            scratch[wv][u][pos] = make_float2(e1, __int_as_float(sl * 128 + 64 + lane));
                    }
                    cnt += __popcll(b1);
                }
                Ms[u] = min(cnt, 64);
            }
            LDS_FENCE();   // drain compaction writes before readback
#pragma unroll
            for (int u = 0; u < 2; ++u) {
                int M = Ms[u];
                float2 own = scratch[wv][u][lane];
                float di = own.x; int ni = __float_as_int(own.y);
                int rank = 0;
                const float2* buf = &scratch[wv][u][0];
#pragma unroll 4
                for (int j = 0; j < M; ++j) {
                    float2 e = buf[j];
                    int nj = __float_as_int(e.y);
                    rank += (e.x < di || (e.x == di && nj < ni)) ? 1 : 0;
                }
                if (lane < M && rank < 16)
                    knnl[wv][(pr + u) * 16 + rank] = ni;   // LDS, not global
            }
            LDS_FENCE();   // order scratch reuse across pairs
        }
    }

    // all 64 knn indices for this wave's 4 queries (wave-local LDS)
    int idxAll = knnl[wv][lane];

    __syncthreads();   // stage buffer dead -> safe to overlay

    // ================= Phase B: MLP =================
    unsigned short* w1a   = (unsigned short*)smem;             // [64][104]
    unsigned short* h1all = (unsigned short*)(smem + 13312);   // 16 x [16][H1STR]
    unsigned short* w2l   = (unsigned short*)(smem + 52224);   // [128][88]
    float*          otile = (float*)(smem + 74752);            // [64][130]
    int col = lane & 15, quad = lane >> 4;
    const uint4* fx4 = (const uint4*)fxtb;
    size_t rowb = (size_t)b * NN;

    // stage weights into LDS (all 1024 threads)
    {
        const unsigned* src1 = (const unsigned*)w1p;   // rows: 96 dw stride
        unsigned* d1 = (unsigned*)w1a;
        for (int t = threadIdx.x; t < 64 * 48; t += 1024) {
            int r = t / 48, c = t - r * 48;
            d1[r * 52 + c] = src1[r * 96 + c];
        }
        const unsigned* src2 = (const unsigned*)w2p;   // rows: 36 dw
        unsigned* d2 = (unsigned*)w2l;
        for (int t = threadIdx.x; t < 128 * 36; t += 1024) {
            int r = t / 36, c = t - r * 36;
            d2[r * 44 + c] = src2[r * 36 + c];
        }
    }

    // qterm: f_q . W1d for this wave's 4 queries (W1d fragments from global)
    f32x4 accq[4];
#pragma unroll
    for (int nt = 0; nt < 4; ++nt) accq[nt] = (f32x4){0.f, 0.f, 0.f, 0.f};
    {
        const uint4* rp = fx4 + (rowb + q0base + wv * 4 + col) * 9;
        uint4 qf0 = rp[quad];
        uint4 qf1 = rp[4 + quad];
        uint4 qf2 = rp[8];
        if (quad != 0) qf2 = make_uint4(0u, 0u, 0u, 0u);
        uint4 qf[3] = {qf0, qf1, qf2};
#pragma unroll
        for (int ks = 0; ks < 3; ++ks) {
            s16x8 a = as8(qf[ks]);
#pragma unroll
            for (int nt = 0; nt < 4; ++nt) {
                s16x8 bfr = *(const s16x8*)(w1p + (nt * 16 + col) * 192 + 96 + ks * 32 + quad * 8);
                accq[nt] = __builtin_amdgcn_mfma_f32_16x16x32_bf16(a, bfr, accq[nt], 0, 0, 0);
            }
        }
    }
    float qcc[4][4];   // qterm + c1, per (query, nt)
    {
        float c1v[4];
#pragma unroll
        for (int nt = 0; nt < 4; ++nt) c1v[nt] = c1[nt * 16 + col];
#pragma unroll
        for (int qi = 0; qi < 4; ++qi)
#pragma unroll
            for (int nt = 0; nt < 4; ++nt)
                qcc[qi][nt] = __shfl(accq[nt][qi], col, 64) + c1v[nt];
    }
    float c2v[8];
#pragma unroll
    for (int nt = 0; nt < 8; ++nt) c2v[nt] = c2[nt * 16 + col];

    __syncthreads();   // staged weights visible to all waves

    unsigned short* h1w = h1all + wv * (16 * H1STR);

    uint4 af[2][3];
#define PREF(buf, qi_) {                                                      \
        int nidx_ = __shfl(idxAll, (qi_) * 16 + col, 64);                     \
        const uint4* rp_ = fx4 + (rowb + nidx_) * 9;                          \
        af[buf][0] = rp_[quad];                                               \
        af[buf][1] = rp_[4 + quad];                                           \
        uint4 f2_ = rp_[8];                                                   \
        af[buf][2] = (quad == 0) ? f2_ : make_uint4(0u, 0u, 0u, 0u); }

    PREF(0, 0);

#pragma unroll
    for (int qi = 0; qi < 4; ++qi) {
        const int cur = qi & 1;
        // GEMM1: A = gathered rows (regs), B = w1a (LDS), acc init = qterm + c1
        f32x4 acc1[4];
#pragma unroll
        for (int nt = 0; nt < 4; ++nt)
            acc1[nt] = (f32x4){qcc[qi][nt], qcc[qi][nt], qcc[qi][nt], qcc[qi][nt]};
#pragma unroll
        for (int ks = 0; ks < 3; ++ks) {
            s16x8 a = as8(af[cur][ks]);
#pragma unroll
            for (int nt = 0; nt < 4; ++nt) {
                s16x8 bfr = *(const s16x8*)(w1a + (nt * 16 + col) * 104 + ks * 32 + quad * 8);
                acc1[nt] = __builtin_amdgcn_mfma_f32_16x16x32_bf16(a, bfr, acc1[nt], 0, 0, 0);
            }
        }
        // kick next query's gather while h1/GEMM2 run
        if (qi < 3) PREF(cur ^ 1, qi + 1);
        // h1 = relu(acc1) -> LDS (wave-private; stride 76 -> 32-bank writes)
#pragma unroll
        for (int nt = 0; nt < 4; ++nt)
#pragma unroll
            for (int rr = 0; rr < 4; ++rr)
                h1w[(quad * 4 + rr) * H1STR + nt * 16 + col] = bf16b(fmaxf(acc1[nt][rr], 0.f));
        LDS_FENCE();
        // GEMM2 + maxpool, A-fragments hoisted (identical for both halves)
        s16x8 a2f[2];
        a2f[0] = *(const s16x8*)(h1w + col * H1STR + quad * 8);
        a2f[1] = *(const s16x8*)(h1w + col * H1STR + 32 + quad * 8);
#pragma unroll
        for (int hf = 0; hf < 2; ++hf) {
            f32x4 acc2[4];
#pragma unroll
            for (int nt = 0; nt < 4; ++nt) acc2[nt] = (f32x4){0.f, 0.f, 0.f, 0.f};
#pragma unroll
            for (int ks = 0; ks < 2; ++ks) {
#pragma unroll
                for (int nt = 0; nt < 4; ++nt) {
                    s16x8 wf = *(const s16x8*)(w2l + ((hf * 4 + nt) * 16 + col) * 88 + ks * 32 + quad * 8);
                    acc2[nt] = __builtin_amdgcn_mfma_f32_16x16x32_bf16(a2f[ks], wf, acc2[nt], 0, 0, 0);
                }
            }
#pragma unroll
            for (int nt = 0; nt < 4; ++nt) {
                float m0 = fmaxf(fmaxf(acc2[nt][0], acc2[nt][1]), fmaxf(acc2[nt][2], acc2[nt][3]));
                m0 = fmaxf(m0 + c2v[hf * 4 + nt], 0.f);
                m0 = fmaxf(m0, __shfl_xor(m0, 16, 64));
                m0 = fmaxf(m0, __shfl_xor(m0, 32, 64));
                if (quad == 0)
                    otile[(wv * 4 + qi) * 130 + (hf * 4 + nt) * 16 + col] = m0;
            }
        }
        LDS_FENCE();   // drain h1 reads before next iteration's overwrite
    }
    __syncthreads();
    // coalesced store: consecutive threads -> consecutive q, same channel
    for (int i = threadIdx.x; i < H2 * 64; i += 1024) {
        int ch = i >> 6, q = i & 63;
        out1[((size_t)(b * H2 + ch)) * PP + q0base + q] = otile[q * 130 + ch];
    }
#undef PREF
}

extern "C" void kernel_launch(void* const* d_in, const int* in_sizes, int n_in,
                              void* d_out, int out_size, void* d_ws, size_t ws_size,
                              hipStream_t stream) {
    const float* xyz  = (const float*)d_in[0];
    const float* feat = (const float*)d_in[1];
    const float* W1   = (const float*)d_in[2];
    const float* b1   = (const float*)d_in[3];
    const float* g1   = (const float*)d_in[4];
    const float* be1  = (const float*)d_in[5];
    const float* m1   = (const float*)d_in[6];
    const float* v1   = (const float*)d_in[7];
    const float* W2   = (const float*)d_in[8];
    const float* b2   = (const float*)d_in[9];
    const float* g2   = (const float*)d_in[10];
    const float* be2  = (const float*)d_in[11];
    const float* m2   = (const float*)d_in[12];
    const float* v2   = (const float*)d_in[13];

    char* ws = (char*)d_ws;
    unsigned*       fxtb = (unsigned*)(ws + OFF_FXT);
    float4*         pts4 = (float4*)(ws + OFF_PTS4);
    unsigned short* w1p  = (unsigned short*)(ws + OFF_W1P);
    unsigned short* w2p  = (unsigned short*)(ws + OFF_W2P);
    float*          c1   = (float*)(ws + OFF_C1);
    float*          c2   = (float*)(ws + OFF_C2);

    float* out0 = (float*)d_out;
    float* out1 = out0 + (size_t)BB * PP * 3;
    float* out2 = out1 + (size_t)BB * H2 * PP;

    hipLaunchKernelGGL(k1_prep, dim3(1024), dim3(512), 0, stream,
                       xyz, feat, fxtb, pts4, out0, out2,
                       W1, b1, g1, be1, m1, v1, W2, b2, g2, be2, m2, v2,
                       w1p, w2p, c1, c2);
    hipLaunchKernelGGL(k23, dim3(256), dim3(1024), 0, stream,
                       pts4, fxtb, w1p, w2p, c1, c2, out1);
}